// Round 4
// baseline (1629.615 us; speedup 1.0000x reference)
//
#include <hip/hip_runtime.h>
#include <math.h>

// Problem constants
#define Bn 256
#define Tn 100
#define In 1024
#define Hn 2048
#define On 10
#define Kc (In + Hn)   // 3072 concatenated K

typedef short s8v  __attribute__((ext_vector_type(8)));   // 8 x bf16 (as raw shorts), 4 VGPRs
typedef unsigned short us4 __attribute__((ext_vector_type(4)));
typedef float f32x4 __attribute__((ext_vector_type(4)));

__device__ __forceinline__ unsigned short f2bf(float f) {
    unsigned int u = __float_as_uint(f);
    u += 0x7fffu + ((u >> 16) & 1u);   // round-to-nearest-even
    return (unsigned short)(u >> 16);
}

// Branch-free exact tanh: 1 - 2/(exp(2x)+1). exp overflow -> inf -> rcp -> 0 -> +1;
// exp underflow -> 0 -> rcp(1) -> -1. ~1e-6 abs err, way under bf16 rounding.
__device__ __forceinline__ float fast_tanh(float x) {
    float e = __expf(x + x);
    return 1.0f - 2.0f * __builtin_amdgcn_rcpf(e + 1.0f);
}

// ---- setup kernels -------------------------------------------------------

// x [B][T][I] fp32 -> bf16, 4 elems/thread
__global__ void conv_x_kernel(const float4* __restrict__ src, ushort4* __restrict__ dst) {
    int i = blockIdx.x * 256 + threadIdx.x;
    float4 v = src[i];
    ushort4 o;
    o.x = f2bf(v.x); o.y = f2bf(v.y); o.z = f2bf(v.z); o.w = f2bf(v.w);
    dst[i] = o;
}

// src [K][N=2048] fp32 -> dst[n][colOff + k] bf16  (builds B^T = [Win;W]^T rows)
__global__ void transpose_bf16_kernel(const float* __restrict__ src, unsigned short* __restrict__ dst,
                                      int N, int ld, int colOff) {
    __shared__ float tile[32][33];
    int k0 = blockIdx.x * 32;
    int n0 = blockIdx.y * 32;
    int c = threadIdx.x & 31;
    int r = threadIdx.x >> 5;            // 0..7
    #pragma unroll
    for (int i = 0; i < 32; i += 8)
        tile[r + i][c] = src[(size_t)(k0 + r + i) * N + n0 + c];
    __syncthreads();
    #pragma unroll
    for (int i = 0; i < 32; i += 8)
        dst[(size_t)(n0 + r + i) * ld + colOff + k0 + c] = f2bf(tile[c][r + i]);
}

// h0 -> h_all slot 0 (bf16); lin_w -> padded bf16 [16][2048]; zero barrier block
__global__ void small_conv_kernel(const float* __restrict__ h0, const float* __restrict__ lin_w,
                                  unsigned short* __restrict__ h_all0, unsigned short* __restrict__ lwb,
                                  unsigned int* __restrict__ bar) {
    int idx = blockIdx.x * 256 + threadIdx.x;
    if (idx < 512) bar[idx] = 0u;        // per-block flags (re-zeroed every launch)
    if (idx < Bn * Hn) {
        h_all0[idx] = f2bf(h0[idx]);
    } else {
        int j = idx - Bn * Hn;           // < 16*2048 exactly (grid sized for it)
        int o = j >> 11;
        int k = j & 2047;
        lwb[j] = (o < On) ? f2bf(lin_w[o * Hn + k]) : (unsigned short)0;
    }
}

// ---- persistent scan -----------------------------------------------------
// R8: 256 blocks x 256 thr (4 waves = 1/SIMD), 1 block/CU. Block tile 64m x
// 32n; n XCD-pinned via blockIdx%8. B-fragments register-resident.
// Rationale (R7b post-mortem): step = 12.2us but single-event latencies sum
// to ~5us -> the h-part's depth-2 ring left ~8 load-RTTs EXPOSED (chunk c+1
// issued only ~40cy before use vs ~700cy burst RTT), and the x-part ran 4
// fully-serialized chunks on the flag->poll chain. At 2 waves/SIMD there was
// no register room to deepen. Fix: HALVE the waves, DOUBLE each wave's
// k-slice, and use the doubled register budget (1 wave/SIMD -> 256 VGPR +
// 256 AGPR) for DEPTH-8 load pipelines:
//  * x-part: all 8 chunks (32 loads) issued before any MFMA -> 1 RTT total.
//  * h-part: 16 chunks, 8-deep ring (32 loads in flight; chunk c+8 issued
//    ~320cy of MFMA ahead) -> ~1 RTT + BW-service instead of 8 exposed RTTs.
//  * LDS reduce: 4 slabs (36KB), one barrier, unchanged mapping.
// Regs (est): A-ring ~144 live VGPR + misc ~45; bx 64 + bh 128 + acc 32 =
// 224 AGPR. MFMA count, traffic, and sync protocol identical to R7b.
// Sync (proven R4-R7b): relaxed agent-scope write-through h stores;
// __syncthreads drains vmcnt(0) before the flag store; per-block flag,
// per-wave 64-lane poll + __all; fresh h addresses each step make plain
// consumer loads safe (no stale L1/L2 lines possible).
__global__ __launch_bounds__(256, 1)
void scan_kernel(const unsigned short* __restrict__ xb,
                 const unsigned short* __restrict__ BTm,
                 unsigned short* __restrict__ h_all,
                 unsigned int* __restrict__ bar) {
    const int g = blockIdx.x;
    const int mg = (g >> 3) & 3;                        // m-group = independent chain
    const int m0 = mg * 64;
    const int n0 = ((g & 7) * 8 + (g >> 5)) * 32;       // 64 n-tiles, XCD-pinned
    const int w = threadIdx.x >> 6;                     // 0..3
    const int lane = threadIdx.x & 63;
    const int quad = lane >> 4;
    const int lr = lane & 15;

    __shared__ float red[4][64][36];                    // pad 36: 2-way banks (free)

    const unsigned short* bp0 = BTm + (size_t)(n0 + lr) * Kc;
    const unsigned short* bp1 = BTm + (size_t)(n0 + 16 + lr) * Kc;

    const size_t xrow = (size_t)Tn * In;                // x row stride (102400)

    // flag layout: bar[mg*64 + xcd*8 + j]  (g = xcd | mg<<3 | j<<5 bijective)
    const int fidx = mg * 64 + (g & 7) * 8 + (g >> 5);
    unsigned int* fl = bar + mg * 64;                   // my group's 64 flags

    // ---- one-time B-fragment preload (lives in AGPRs all 100 steps) ----
    s8v bx[8][2];                                       // x-region B frags (k = w*256..+256)
    s8v bh[16][2];                                      // h-region B frags (k = w*512..+512)
    #pragma unroll
    for (int c = 0; c < 8; ++c) {
        const int kq = w * 256 + c * 32 + quad * 8;
        bx[c][0] = *(const s8v*)(bp0 + kq);
        bx[c][1] = *(const s8v*)(bp1 + kq);
    }
    #pragma unroll
    for (int c = 0; c < 16; ++c) {
        const int kq = In + w * 512 + c * 32 + quad * 8;
        bh[c][0] = *(const s8v*)(bp0 + kq);
        bh[c][1] = *(const s8v*)(bp1 + kq);
    }

    f32x4 acc[4][2];
    #pragma unroll
    for (int mi = 0; mi < 4; ++mi)
        #pragma unroll
        for (int ni = 0; ni < 2; ++ni)
            acc[mi][ni] = (f32x4){0.f, 0.f, 0.f, 0.f};

    // ---- x-part for t=0 (all 8 chunks in flight before first MFMA) ----
    {
        const unsigned short* ar = xb + w * 256 + quad * 8 + (size_t)(m0 + lr) * xrow;
        s8v X[8][4];
        #pragma unroll
        for (int c = 0; c < 8; ++c)
            #pragma unroll
            for (int r = 0; r < 4; ++r)
                X[c][r] = *(const s8v*)(ar + c * 32 + r * 16 * xrow);
        #pragma unroll
        for (int c = 0; c < 8; ++c) {
            acc[0][0] = __builtin_amdgcn_mfma_f32_16x16x32_bf16(X[c][0], bx[c][0], acc[0][0], 0, 0, 0);
            acc[1][0] = __builtin_amdgcn_mfma_f32_16x16x32_bf16(X[c][1], bx[c][0], acc[1][0], 0, 0, 0);
            acc[2][0] = __builtin_amdgcn_mfma_f32_16x16x32_bf16(X[c][2], bx[c][0], acc[2][0], 0, 0, 0);
            acc[3][0] = __builtin_amdgcn_mfma_f32_16x16x32_bf16(X[c][3], bx[c][0], acc[3][0], 0, 0, 0);
            acc[0][1] = __builtin_amdgcn_mfma_f32_16x16x32_bf16(X[c][0], bx[c][1], acc[0][1], 0, 0, 0);
            acc[1][1] = __builtin_amdgcn_mfma_f32_16x16x32_bf16(X[c][1], bx[c][1], acc[1][1], 0, 0, 0);
            acc[2][1] = __builtin_amdgcn_mfma_f32_16x16x32_bf16(X[c][2], bx[c][1], acc[2][1], 0, 0, 0);
            acc[3][1] = __builtin_amdgcn_mfma_f32_16x16x32_bf16(X[c][3], bx[c][1], acc[3][1], 0, 0, 0);
        }
    }

    for (int t = 0; t < Tn; ++t) {
        // ---- h-part: 16 chunks, 8-deep ring (32 loads in flight) ----
        const unsigned short* hr = h_all + (size_t)t * (Bn * Hn)
                                 + (size_t)(m0 + lr) * Hn + w * 512 + quad * 8;
        s8v A[16][4];                                   // virtual; ~9 slots live at peak
        #pragma unroll
        for (int c = 0; c < 8; ++c)
            #pragma unroll
            for (int r = 0; r < 4; ++r)
                A[c][r] = *(const s8v*)(hr + c * 32 + r * 16 * Hn);
        #pragma unroll
        for (int c = 0; c < 16; ++c) {
            if (c < 8) {                                // prefetch chunk c+8
                #pragma unroll
                for (int r = 0; r < 4; ++r)
                    A[c + 8][r] = *(const s8v*)(hr + (c + 8) * 32 + r * 16 * Hn);
            }
            acc[0][0] = __builtin_amdgcn_mfma_f32_16x16x32_bf16(A[c][0], bh[c][0], acc[0][0], 0, 0, 0);
            acc[1][0] = __builtin_amdgcn_mfma_f32_16x16x32_bf16(A[c][1], bh[c][0], acc[1][0], 0, 0, 0);
            acc[2][0] = __builtin_amdgcn_mfma_f32_16x16x32_bf16(A[c][2], bh[c][0], acc[2][0], 0, 0, 0);
            acc[3][0] = __builtin_amdgcn_mfma_f32_16x16x32_bf16(A[c][3], bh[c][0], acc[3][0], 0, 0, 0);
            acc[0][1] = __builtin_amdgcn_mfma_f32_16x16x32_bf16(A[c][0], bh[c][1], acc[0][1], 0, 0, 0);
            acc[1][1] = __builtin_amdgcn_mfma_f32_16x16x32_bf16(A[c][1], bh[c][1], acc[1][1], 0, 0, 0);
            acc[2][1] = __builtin_amdgcn_mfma_f32_16x16x32_bf16(A[c][2], bh[c][1], acc[2][1], 0, 0, 0);
            acc[3][1] = __builtin_amdgcn_mfma_f32_16x16x32_bf16(A[c][3], bh[c][1], acc[3][1], 0, 0, 0);
        }

        // ---- LDS reduce: C/D layout row=quad*4+reg, col=lane&15 [m89/m91] ----
        // 4 waves -> 4 slabs, each wave its own, ONE barrier.
        #pragma unroll
        for (int mi = 0; mi < 4; ++mi)
            #pragma unroll
            for (int ni = 0; ni < 2; ++ni)
                #pragma unroll
                for (int rr = 0; rr < 4; ++rr)
                    red[w][mi * 16 + quad * 4 + rr][ni * 16 + lr] = acc[mi][ni][rr];
        __syncthreads();

        {   // final reduce + tanh + agent-scope write-through store (2 x 8 B)
            int j = threadIdx.x << 3;                   // 8 elems/thread
            int row = j >> 5;                           // 0..63
            int c0 = j & 31;                            // 0,8,16,24
            float4 a0 = *(const float4*)&red[0][row][c0];
            float4 a1 = *(const float4*)&red[1][row][c0];
            float4 a2 = *(const float4*)&red[2][row][c0];
            float4 a3 = *(const float4*)&red[3][row][c0];
            float4 b0 = *(const float4*)&red[0][row][c0 + 4];
            float4 b1 = *(const float4*)&red[1][row][c0 + 4];
            float4 b2 = *(const float4*)&red[2][row][c0 + 4];
            float4 b3 = *(const float4*)&red[3][row][c0 + 4];
            us4 oA, oB;
            oA[0] = f2bf(fast_tanh((a0.x + a1.x) + (a2.x + a3.x)));
            oA[1] = f2bf(fast_tanh((a0.y + a1.y) + (a2.y + a3.y)));
            oA[2] = f2bf(fast_tanh((a0.z + a1.z) + (a2.z + a3.z)));
            oA[3] = f2bf(fast_tanh((a0.w + a1.w) + (a2.w + a3.w)));
            oB[0] = f2bf(fast_tanh((b0.x + b1.x) + (b2.x + b3.x)));
            oB[1] = f2bf(fast_tanh((b0.y + b1.y) + (b2.y + b3.y)));
            oB[2] = f2bf(fast_tanh((b0.z + b1.z) + (b2.z + b3.z)));
            oB[3] = f2bf(fast_tanh((b0.w + b1.w) + (b2.w + b3.w)));
            unsigned long long* dst = (unsigned long long*)
                (h_all + (size_t)(t + 1) * (Bn * Hn) + (size_t)(m0 + row) * Hn + n0 + c0);
            __hip_atomic_store(dst, __builtin_bit_cast(unsigned long long, oA),
                               __ATOMIC_RELAXED, __HIP_MEMORY_SCOPE_AGENT);
            __hip_atomic_store(dst + 1, __builtin_bit_cast(unsigned long long, oB),
                               __ATOMIC_RELAXED, __HIP_MEMORY_SCOPE_AGENT);
        }

        if (t < Tn - 1) {
            __syncthreads();                             // per-wave vmcnt(0): h stores drained
            const unsigned int tp1 = (unsigned int)(t + 1);

            // ---- ARRIVE: one contention-free flag store ----
            if (threadIdx.x == 0)
                __hip_atomic_store(bar + fidx, tp1, __ATOMIC_RELAXED,
                                   __HIP_MEMORY_SCOPE_AGENT);

            // ---- x-part of t+1 fills the poll window (all loads upfront) ----
            #pragma unroll
            for (int mi = 0; mi < 4; ++mi)
                #pragma unroll
                for (int ni = 0; ni < 2; ++ni)
                    acc[mi][ni] = (f32x4){0.f, 0.f, 0.f, 0.f};
            const unsigned short* ar = xb + (size_t)(t + 1) * In + w * 256 + quad * 8
                                     + (size_t)(m0 + lr) * xrow;
            s8v X[8][4];
            #pragma unroll
            for (int c = 0; c < 8; ++c)
                #pragma unroll
                for (int r = 0; r < 4; ++r)
                    X[c][r] = *(const s8v*)(ar + c * 32 + r * 16 * xrow);
            #pragma unroll
            for (int c = 0; c < 8; ++c) {
                acc[0][0] = __builtin_amdgcn_mfma_f32_16x16x32_bf16(X[c][0], bx[c][0], acc[0][0], 0, 0, 0);
                acc[1][0] = __builtin_amdgcn_mfma_f32_16x16x32_bf16(X[c][1], bx[c][0], acc[1][0], 0, 0, 0);
                acc[2][0] = __builtin_amdgcn_mfma_f32_16x16x32_bf16(X[c][2], bx[c][0], acc[2][0], 0, 0, 0);
                acc[3][0] = __builtin_amdgcn_mfma_f32_16x16x32_bf16(X[c][3], bx[c][0], acc[3][0], 0, 0, 0);
                acc[0][1] = __builtin_amdgcn_mfma_f32_16x16x32_bf16(X[c][0], bx[c][1], acc[0][1], 0, 0, 0);
                acc[1][1] = __builtin_amdgcn_mfma_f32_16x16x32_bf16(X[c][1], bx[c][1], acc[1][1], 0, 0, 0);
                acc[2][1] = __builtin_amdgcn_mfma_f32_16x16x32_bf16(X[c][2], bx[c][1], acc[2][1], 0, 0, 0);
                acc[3][1] = __builtin_amdgcn_mfma_f32_16x16x32_bf16(X[c][3], bx[c][1], acc[3][1], 0, 0, 0);
            }

            // ---- per-wave poll: 64 lanes check 64 group flags in one load ----
            while (true) {
                unsigned int v = __hip_atomic_load(fl + lane, __ATOMIC_RELAXED,
                                                   __HIP_MEMORY_SCOPE_AGENT);
                if (__all((int)(v >= tp1))) break;
                __builtin_amdgcn_s_sleep(1);
            }
            asm volatile("" ::: "memory");               // no load hoisting above the poll
        }
    }
}

// ---- output projection ---------------------------------------------------
// y[b][t][o] = h_all[t+1][b][:] . lin_w[o][:] + lin_b[o]. One 16-row wave per 16 (t,b) rows.
__global__ __launch_bounds__(256)
void gemm2_kernel(const unsigned short* __restrict__ h_all, const unsigned short* __restrict__ lwb,
                  const float* __restrict__ lb, float* __restrict__ y) {
    int gw = blockIdx.x * 4 + (threadIdx.x >> 6);       // 0..1599
    int lane = threadIdx.x & 63, quad = lane >> 4, lr = lane & 15;
    int m0 = gw * 16;
    int t = m0 >> 8;
    int b0 = m0 & 255;
    const unsigned short* ah = h_all + ((size_t)(t + 1) * Bn + b0 + lr) * Hn + quad * 8;
    const unsigned short* bh = lwb + (size_t)lr * Hn + quad * 8;
    f32x4 acc0 = {0.f, 0.f, 0.f, 0.f}, acc1 = {0.f, 0.f, 0.f, 0.f};
    #pragma unroll
    for (int k0 = 0; k0 < Hn; k0 += 64) {
        s8v a0 = *(const s8v*)(ah + k0);
        s8v b0 = *(const s8v*)(bh + k0);
        acc0 = __builtin_amdgcn_mfma_f32_16x16x32_bf16(a0, b0, acc0, 0, 0, 0);
        s8v a1 = *(const s8v*)(ah + k0 + 32);
        s8v b1 = *(const s8v*)(bh + k0 + 32);
        acc1 = __builtin_amdgcn_mfma_f32_16x16x32_bf16(a1, b1, acc1, 0, 0, 0);
    }
    acc0 = acc0 + acc1;
    if (lr < On) {
        float bias = lb[lr];
        #pragma unroll
        for (int rr = 0; rr < 4; ++rr) {
            int b = b0 + quad * 4 + rr;
            y[(size_t)b * (Tn * On) + t * On + lr] = acc0[rr] + bias;
        }
    }
}

// ---- host ----------------------------------------------------------------

extern "C" void kernel_launch(void* const* d_in, const int* in_sizes, int n_in,
                              void* d_out, int out_size, void* d_ws, size_t ws_size,
                              hipStream_t stream) {
    const float* x   = (const float*)d_in[0];
    const float* h0  = (const float*)d_in[1];
    const float* Win = (const float*)d_in[2];
    const float* W   = (const float*)d_in[3];
    const float* lw  = (const float*)d_in[4];
    const float* lb  = (const float*)d_in[5];
    float* y = (float*)d_out;

    // ws layout (bf16 elems): ~171 MB total
    unsigned short* ws    = (unsigned short*)d_ws;
    unsigned short* xb    = ws;                                  // 26,214,400 elems
    unsigned short* BTm   = xb + (size_t)Bn * Tn * In;           //  6,291,456 elems [2048][3072]
    unsigned short* h_all = BTm + (size_t)Hn * Kc;               // 52,953,088 elems [(T+1)][B][H]
    unsigned short* lwb   = h_all + (size_t)(Tn + 1) * Bn * Hn;  //     32,768 elems [16][2048]
    unsigned int*   bar   = (unsigned int*)(lwb + 32768);        // 512 uints flag block

    conv_x_kernel<<<25600, 256, 0, stream>>>((const float4*)x, (ushort4*)xb);
    transpose_bf16_kernel<<<dim3(32, 64), 256, 0, stream>>>(Win, BTm, Hn, Kc, 0);
    transpose_bf16_kernel<<<dim3(64, 64), 256, 0, stream>>>(W, BTm, Hn, Kc, In);
    small_conv_kernel<<<2176, 256, 0, stream>>>(h0, lw, h_all, lwb, bar);

    scan_kernel<<<256, 256, 0, stream>>>(xb, BTm, h_all, bar);

    gemm2_kernel<<<400, 256, 0, stream>>>(h_all, lwb, lb, y);
}

// Round 5
// 1377.992 us; speedup vs baseline: 1.1826x; 1.1826x over previous
//
#include <hip/hip_runtime.h>
#include <math.h>

// Problem constants
#define Bn 256
#define Tn 100
#define In 1024
#define Hn 2048
#define On 10
#define Kc (In + Hn)   // 3072 concatenated K

typedef short s8v  __attribute__((ext_vector_type(8)));   // 8 x bf16 (as raw shorts), 4 VGPRs
typedef unsigned short us4 __attribute__((ext_vector_type(4)));
typedef float f32x4 __attribute__((ext_vector_type(4)));

__device__ __forceinline__ unsigned short f2bf(float f) {
    unsigned int u = __float_as_uint(f);
    u += 0x7fffu + ((u >> 16) & 1u);   // round-to-nearest-even
    return (unsigned short)(u >> 16);
}

// Branch-free exact tanh: 1 - 2/(exp(2x)+1). exp overflow -> inf -> rcp -> 0 -> +1;
// exp underflow -> 0 -> rcp(1) -> -1. ~1e-6 abs err, way under bf16 rounding.
__device__ __forceinline__ float fast_tanh(float x) {
    float e = __expf(x + x);
    return 1.0f - 2.0f * __builtin_amdgcn_rcpf(e + 1.0f);
}

// ---- setup kernels -------------------------------------------------------

// x [B][T][I] fp32 -> bf16, 4 elems/thread
__global__ void conv_x_kernel(const float4* __restrict__ src, ushort4* __restrict__ dst) {
    int i = blockIdx.x * 256 + threadIdx.x;
    float4 v = src[i];
    ushort4 o;
    o.x = f2bf(v.x); o.y = f2bf(v.y); o.z = f2bf(v.z); o.w = f2bf(v.w);
    dst[i] = o;
}

// src [K][N=2048] fp32 -> dst[n][colOff + k] bf16  (builds B^T = [Win;W]^T rows)
__global__ void transpose_bf16_kernel(const float* __restrict__ src, unsigned short* __restrict__ dst,
                                      int N, int ld, int colOff) {
    __shared__ float tile[32][33];
    int k0 = blockIdx.x * 32;
    int n0 = blockIdx.y * 32;
    int c = threadIdx.x & 31;
    int r = threadIdx.x >> 5;            // 0..7
    #pragma unroll
    for (int i = 0; i < 32; i += 8)
        tile[r + i][c] = src[(size_t)(k0 + r + i) * N + n0 + c];
    __syncthreads();
    #pragma unroll
    for (int i = 0; i < 32; i += 8)
        dst[(size_t)(n0 + r + i) * ld + colOff + k0 + c] = f2bf(tile[c][r + i]);
}

// h0 -> h_all slot 0 (bf16); lin_w -> padded bf16 [16][2048]; zero barrier block
__global__ void small_conv_kernel(const float* __restrict__ h0, const float* __restrict__ lin_w,
                                  unsigned short* __restrict__ h_all0, unsigned short* __restrict__ lwb,
                                  unsigned int* __restrict__ bar) {
    int idx = blockIdx.x * 256 + threadIdx.x;
    if (idx < 512) bar[idx] = 0u;        // per-block flags (re-zeroed every launch)
    if (idx < Bn * Hn) {
        h_all0[idx] = f2bf(h0[idx]);
    } else {
        int j = idx - Bn * Hn;           // < 16*2048 exactly (grid sized for it)
        int o = j >> 11;
        int k = j & 2047;
        lwb[j] = (o < On) ? f2bf(lin_w[o * Hn + k]) : (unsigned short)0;
    }
}

// ---- persistent scan -----------------------------------------------------
// R9 = R7b structure (8 waves = 2/SIMD, depth-2 h ring, flag barrier, 8-slab
// reduce, one 8B store/thread) + XCD-PAIR-PINNED M-GROUPS.
// R8 post-mortem: dur == hbm_bytes/hbm_gbps in BOTH R7b and R8 -> the scan
// runs at the speed of latency-limited HBM traffic (~600 GB/s eff, not the
// 6.3 TB/s ceiling). FETCH=621MB vs ~65MB ideal: ~5.6MB/step of h-reads come
// from HBM because the old mapping put all 4 m-groups on EVERY XCD -> each
// of the 8 non-coherent L2s re-fetched the whole 1MB h slab every step.
// R9 mapping (XCD = blockIdx%8 heuristic; perf-only, sync is mapping-proof):
//   mg = (g&7)>>1  -> m-group pinned to XCD pair {2mg, 2mg+1}
//   n0 = ((g>>3)*2 + (g&1))*32 -> the pair's 64 blocks cover the 64 n-tiles
// Every h row is produced AND consumed inside one XCD pair: same-XCD
// consumers hit the producer XCD's L2 (write-through leaves line valid
// locally), pair-partner consumers hit L3. h -> ~0 HBM fetch; the h-load
// chain RTT drops ~3-4x.
// Sync (proven R4-R7b): relaxed agent-scope write-through h stores;
// __syncthreads drains vmcnt(0) before the flag store; per-block flag,
// per-wave 64-lane poll + __all; fresh h addresses each step make plain
// consumer loads safe (no stale L1/L2 lines possible).
__global__ __launch_bounds__(512, 2)
void scan_kernel(const unsigned short* __restrict__ xb,
                 const unsigned short* __restrict__ BTm,
                 unsigned short* __restrict__ h_all,
                 unsigned int* __restrict__ bar) {
    const int g = blockIdx.x;
    const int mg = (g & 7) >> 1;                        // m-group = XCD pair
    const int m0 = mg * 64;
    const int n0 = ((g >> 3) * 2 + (g & 1)) * 32;       // 64 n-tiles per pair
    const int w = threadIdx.x >> 6;                     // 0..7
    const int lane = threadIdx.x & 63;
    const int quad = lane >> 4;
    const int lr = lane & 15;

    __shared__ float red[8][64][36];                    // pad 36: 2-way banks (free)

    const unsigned short* bp0 = BTm + (size_t)(n0 + lr) * Kc;
    const unsigned short* bp1 = BTm + (size_t)(n0 + 16 + lr) * Kc;

    const size_t xrow = (size_t)Tn * In;                // x row stride (102400)

    // flag layout: bar[mg*64 + (g&1)*32 + (g>>3)]  (bijective per group)
    const int fidx = mg * 64 + (g & 1) * 32 + (g >> 3);
    unsigned int* fl = bar + mg * 64;                   // my group's 64 flags

    // ---- one-time B-fragment preload (lives in registers all 100 steps) ----
    s8v bx[4][2];                                       // x-region B frags
    s8v bh[8][2];                                       // h-region B frags
    #pragma unroll
    for (int c = 0; c < 4; ++c) {
        const int kq = w * 128 + c * 32 + quad * 8;
        bx[c][0] = *(const s8v*)(bp0 + kq);
        bx[c][1] = *(const s8v*)(bp1 + kq);
    }
    #pragma unroll
    for (int c = 0; c < 8; ++c) {
        const int kq = In + w * 256 + c * 32 + quad * 8;
        bh[c][0] = *(const s8v*)(bp0 + kq);
        bh[c][1] = *(const s8v*)(bp1 + kq);
    }

    f32x4 acc[4][2];
    #pragma unroll
    for (int mi = 0; mi < 4; ++mi)
        #pragma unroll
        for (int ni = 0; ni < 2; ++ni)
            acc[mi][ni] = (f32x4){0.f, 0.f, 0.f, 0.f};

    // ---- x-part for t=0 ----
    {
        const unsigned short* xt = xb + 0 * In;
        #pragma unroll
        for (int c = 0; c < 4; ++c) {
            const int kq = w * 128 + c * 32 + quad * 8;
            const unsigned short* arow = xt + kq + (size_t)(m0 + lr) * xrow;
            s8v a0 = *(const s8v*)(arow);
            s8v a1 = *(const s8v*)(arow + 16 * xrow);
            s8v a2 = *(const s8v*)(arow + 32 * xrow);
            s8v a3 = *(const s8v*)(arow + 48 * xrow);
            acc[0][0] = __builtin_amdgcn_mfma_f32_16x16x32_bf16(a0, bx[c][0], acc[0][0], 0, 0, 0);
            acc[1][0] = __builtin_amdgcn_mfma_f32_16x16x32_bf16(a1, bx[c][0], acc[1][0], 0, 0, 0);
            acc[2][0] = __builtin_amdgcn_mfma_f32_16x16x32_bf16(a2, bx[c][0], acc[2][0], 0, 0, 0);
            acc[3][0] = __builtin_amdgcn_mfma_f32_16x16x32_bf16(a3, bx[c][0], acc[3][0], 0, 0, 0);
            acc[0][1] = __builtin_amdgcn_mfma_f32_16x16x32_bf16(a0, bx[c][1], acc[0][1], 0, 0, 0);
            acc[1][1] = __builtin_amdgcn_mfma_f32_16x16x32_bf16(a1, bx[c][1], acc[1][1], 0, 0, 0);
            acc[2][1] = __builtin_amdgcn_mfma_f32_16x16x32_bf16(a2, bx[c][1], acc[2][1], 0, 0, 0);
            acc[3][1] = __builtin_amdgcn_mfma_f32_16x16x32_bf16(a3, bx[c][1], acc[3][1], 0, 0, 0);
        }
    }

    for (int t = 0; t < Tn; ++t) {
        // ---- h-part (gated on the per-wave poll of step t-1) ----
        // depth-2 ring: chunk c+1 issued under chunk c's MFMAs (proven R6)
        const unsigned short* hrow = h_all + (size_t)t * (Bn * Hn)
                                   + (size_t)(m0 + lr) * Hn + w * 256 + quad * 8;
        s8v A[2][4];
        #pragma unroll
        for (int r = 0; r < 4; ++r)
            A[0][r] = *(const s8v*)(hrow + r * 16 * Hn);
        #pragma unroll
        for (int c = 0; c < 8; ++c) {
            if (c < 7) {
                const unsigned short* p = hrow + (c + 1) * 32;
                #pragma unroll
                for (int r = 0; r < 4; ++r)
                    A[(c + 1) & 1][r] = *(const s8v*)(p + r * 16 * Hn);
            }
            const s8v a0 = A[c & 1][0];
            const s8v a1 = A[c & 1][1];
            const s8v a2 = A[c & 1][2];
            const s8v a3 = A[c & 1][3];
            acc[0][0] = __builtin_amdgcn_mfma_f32_16x16x32_bf16(a0, bh[c][0], acc[0][0], 0, 0, 0);
            acc[1][0] = __builtin_amdgcn_mfma_f32_16x16x32_bf16(a1, bh[c][0], acc[1][0], 0, 0, 0);
            acc[2][0] = __builtin_amdgcn_mfma_f32_16x16x32_bf16(a2, bh[c][0], acc[2][0], 0, 0, 0);
            acc[3][0] = __builtin_amdgcn_mfma_f32_16x16x32_bf16(a3, bh[c][0], acc[3][0], 0, 0, 0);
            acc[0][1] = __builtin_amdgcn_mfma_f32_16x16x32_bf16(a0, bh[c][1], acc[0][1], 0, 0, 0);
            acc[1][1] = __builtin_amdgcn_mfma_f32_16x16x32_bf16(a1, bh[c][1], acc[1][1], 0, 0, 0);
            acc[2][1] = __builtin_amdgcn_mfma_f32_16x16x32_bf16(a2, bh[c][1], acc[2][1], 0, 0, 0);
            acc[3][1] = __builtin_amdgcn_mfma_f32_16x16x32_bf16(a3, bh[c][1], acc[3][1], 0, 0, 0);
        }

        // ---- LDS reduce: C/D layout row=quad*4+reg, col=lane&15 [m89/m91] ----
        // every wave writes its own slab; ONE barrier; final pass sums 8.
        #pragma unroll
        for (int mi = 0; mi < 4; ++mi)
            #pragma unroll
            for (int ni = 0; ni < 2; ++ni)
                #pragma unroll
                for (int rr = 0; rr < 4; ++rr)
                    red[w][mi * 16 + quad * 4 + rr][ni * 16 + lr] = acc[mi][ni][rr];
        __syncthreads();

        {   // final reduce + tanh + agent-scope write-through store (8 B)
            int j = threadIdx.x << 2;
            int row = j >> 5;
            int c0 = j & 31;
            float4 s0 = *(const float4*)&red[0][row][c0];
            float4 s1 = *(const float4*)&red[1][row][c0];
            float4 s2 = *(const float4*)&red[2][row][c0];
            float4 s3 = *(const float4*)&red[3][row][c0];
            float4 s4 = *(const float4*)&red[4][row][c0];
            float4 s5 = *(const float4*)&red[5][row][c0];
            float4 s6 = *(const float4*)&red[6][row][c0];
            float4 s7 = *(const float4*)&red[7][row][c0];
            us4 o4;
            o4[0] = f2bf(fast_tanh(((s0.x + s1.x) + (s2.x + s3.x)) + ((s4.x + s5.x) + (s6.x + s7.x))));
            o4[1] = f2bf(fast_tanh(((s0.y + s1.y) + (s2.y + s3.y)) + ((s4.y + s5.y) + (s6.y + s7.y))));
            o4[2] = f2bf(fast_tanh(((s0.z + s1.z) + (s2.z + s3.z)) + ((s4.z + s5.z) + (s6.z + s7.z))));
            o4[3] = f2bf(fast_tanh(((s0.w + s1.w) + (s2.w + s3.w)) + ((s4.w + s5.w) + (s6.w + s7.w))));
            unsigned long long* dst = (unsigned long long*)
                (h_all + (size_t)(t + 1) * (Bn * Hn) + (size_t)(m0 + row) * Hn + n0 + c0);
            __hip_atomic_store(dst, __builtin_bit_cast(unsigned long long, o4),
                               __ATOMIC_RELAXED, __HIP_MEMORY_SCOPE_AGENT);
        }

        if (t < Tn - 1) {
            __syncthreads();                             // per-wave vmcnt(0): h stores drained
            const unsigned int tp1 = (unsigned int)(t + 1);

            // ---- ARRIVE: one contention-free flag store ----
            if (threadIdx.x == 0)
                __hip_atomic_store(bar + fidx, tp1, __ATOMIC_RELAXED,
                                   __HIP_MEMORY_SCOPE_AGENT);

            // ---- x-part of t+1 fills the poll window ----
            #pragma unroll
            for (int mi = 0; mi < 4; ++mi)
                #pragma unroll
                for (int ni = 0; ni < 2; ++ni)
                    acc[mi][ni] = (f32x4){0.f, 0.f, 0.f, 0.f};
            const unsigned short* xt = xb + (size_t)(t + 1) * In;
            #pragma unroll
            for (int c = 0; c < 4; ++c) {
                const int kq = w * 128 + c * 32 + quad * 8;
                const unsigned short* arow = xt + kq + (size_t)(m0 + lr) * xrow;
                s8v a0 = *(const s8v*)(arow);
                s8v a1 = *(const s8v*)(arow + 16 * xrow);
                s8v a2 = *(const s8v*)(arow + 32 * xrow);
                s8v a3 = *(const s8v*)(arow + 48 * xrow);
                acc[0][0] = __builtin_amdgcn_mfma_f32_16x16x32_bf16(a0, bx[c][0], acc[0][0], 0, 0, 0);
                acc[1][0] = __builtin_amdgcn_mfma_f32_16x16x32_bf16(a1, bx[c][0], acc[1][0], 0, 0, 0);
                acc[2][0] = __builtin_amdgcn_mfma_f32_16x16x32_bf16(a2, bx[c][0], acc[2][0], 0, 0, 0);
                acc[3][0] = __builtin_amdgcn_mfma_f32_16x16x32_bf16(a3, bx[c][0], acc[3][0], 0, 0, 0);
                acc[0][1] = __builtin_amdgcn_mfma_f32_16x16x32_bf16(a0, bx[c][1], acc[0][1], 0, 0, 0);
                acc[1][1] = __builtin_amdgcn_mfma_f32_16x16x32_bf16(a1, bx[c][1], acc[1][1], 0, 0, 0);
                acc[2][1] = __builtin_amdgcn_mfma_f32_16x16x32_bf16(a2, bx[c][1], acc[2][1], 0, 0, 0);
                acc[3][1] = __builtin_amdgcn_mfma_f32_16x16x32_bf16(a3, bx[c][1], acc[3][1], 0, 0, 0);
            }

            // ---- per-wave poll: 64 lanes check 64 group flags in one load ----
            while (true) {
                unsigned int v = __hip_atomic_load(fl + lane, __ATOMIC_RELAXED,
                                                   __HIP_MEMORY_SCOPE_AGENT);
                if (__all((int)(v >= tp1))) break;
                __builtin_amdgcn_s_sleep(1);
            }
            asm volatile("" ::: "memory");               // no load hoisting above the poll
        }
    }
}

// ---- output projection ---------------------------------------------------
// y[b][t][o] = h_all[t+1][b][:] . lin_w[o][:] + lin_b[o]. One 16-row wave per 16 (t,b) rows.
__global__ __launch_bounds__(256)
void gemm2_kernel(const unsigned short* __restrict__ h_all, const unsigned short* __restrict__ lwb,
                  const float* __restrict__ lb, float* __restrict__ y) {
    int gw = blockIdx.x * 4 + (threadIdx.x >> 6);       // 0..1599
    int lane = threadIdx.x & 63, quad = lane >> 4, lr = lane & 15;
    int m0 = gw * 16;
    int t = m0 >> 8;
    int b0 = m0 & 255;
    const unsigned short* ah = h_all + ((size_t)(t + 1) * Bn + b0 + lr) * Hn + quad * 8;
    const unsigned short* bh = lwb + (size_t)lr * Hn + quad * 8;
    f32x4 acc0 = {0.f, 0.f, 0.f, 0.f}, acc1 = {0.f, 0.f, 0.f, 0.f};
    #pragma unroll
    for (int k0 = 0; k0 < Hn; k0 += 64) {
        s8v a0 = *(const s8v*)(ah + k0);
        s8v b0 = *(const s8v*)(bh + k0);
        acc0 = __builtin_amdgcn_mfma_f32_16x16x32_bf16(a0, b0, acc0, 0, 0, 0);
        s8v a1 = *(const s8v*)(ah + k0 + 32);
        s8v b1 = *(const s8v*)(bh + k0 + 32);
        acc1 = __builtin_amdgcn_mfma_f32_16x16x32_bf16(a1, b1, acc1, 0, 0, 0);
    }
    acc0 = acc0 + acc1;
    if (lr < On) {
        float bias = lb[lr];
        #pragma unroll
        for (int rr = 0; rr < 4; ++rr) {
            int b = b0 + quad * 4 + rr;
            y[(size_t)b * (Tn * On) + t * On + lr] = acc0[rr] + bias;
        }
    }
}

// ---- host ----------------------------------------------------------------

extern "C" void kernel_launch(void* const* d_in, const int* in_sizes, int n_in,
                              void* d_out, int out_size, void* d_ws, size_t ws_size,
                              hipStream_t stream) {
    const float* x   = (const float*)d_in[0];
    const float* h0  = (const float*)d_in[1];
    const float* Win = (const float*)d_in[2];
    const float* W   = (const float*)d_in[3];
    const float* lw  = (const float*)d_in[4];
    const float* lb  = (const float*)d_in[5];
    float* y = (float*)d_out;

    // ws layout (bf16 elems): ~171 MB total
    unsigned short* ws    = (unsigned short*)d_ws;
    unsigned short* xb    = ws;                                  // 26,214,400 elems
    unsigned short* BTm   = xb + (size_t)Bn * Tn * In;           //  6,291,456 elems [2048][3072]
    unsigned short* h_all = BTm + (size_t)Hn * Kc;               // 52,953,088 elems [(T+1)][B][H]
    unsigned short* lwb   = h_all + (size_t)(Tn + 1) * Bn * Hn;  //     32,768 elems [16][2048]
    unsigned int*   bar   = (unsigned int*)(lwb + 32768);        // 512 uints flag block

    conv_x_kernel<<<25600, 256, 0, stream>>>((const float4*)x, (ushort4*)xb);
    transpose_bf16_kernel<<<dim3(32, 64), 256, 0, stream>>>(Win, BTm, Hn, Kc, 0);
    transpose_bf16_kernel<<<dim3(64, 64), 256, 0, stream>>>(W, BTm, Hn, Kc, In);
    small_conv_kernel<<<2176, 256, 0, stream>>>(h0, lw, h_all, lwb, bar);

    scan_kernel<<<256, 512, 0, stream>>>(xb, BTm, h_all, bar);

    gemm2_kernel<<<400, 256, 0, stream>>>(h_all, lwb, lb, y);
}

// Round 6
// 1313.465 us; speedup vs baseline: 1.2407x; 1.0491x over previous
//
#include <hip/hip_runtime.h>
#include <math.h>

// Problem constants
#define Bn 256
#define Tn 100
#define In 1024
#define Hn 2048
#define On 10
#define Kc (In + Hn)   // 3072 concatenated K

typedef short s8v  __attribute__((ext_vector_type(8)));   // 8 x bf16 (as raw shorts), 4 VGPRs
typedef unsigned short us4 __attribute__((ext_vector_type(4)));
typedef float f32x4 __attribute__((ext_vector_type(4)));

__device__ __forceinline__ unsigned short f2bf(float f) {
    unsigned int u = __float_as_uint(f);
    u += 0x7fffu + ((u >> 16) & 1u);   // round-to-nearest-even
    return (unsigned short)(u >> 16);
}

// Branch-free exact tanh: 1 - 2/(exp(2x)+1). ~1e-6 abs err, under bf16 rounding.
__device__ __forceinline__ float fast_tanh(float x) {
    float e = __expf(x + x);
    return 1.0f - 2.0f * __builtin_amdgcn_rcpf(e + 1.0f);
}

// ---- setup kernels -------------------------------------------------------

// x [B][T][I] fp32 -> bf16, 4 elems/thread
__global__ void conv_x_kernel(const float4* __restrict__ src, ushort4* __restrict__ dst) {
    int i = blockIdx.x * 256 + threadIdx.x;
    float4 v = src[i];
    ushort4 o;
    o.x = f2bf(v.x); o.y = f2bf(v.y); o.z = f2bf(v.z); o.w = f2bf(v.w);
    dst[i] = o;
}

// src [K][N=2048] fp32 -> dst[n][colOff + k] bf16  (builds B^T = [Win;W]^T rows)
__global__ void transpose_bf16_kernel(const float* __restrict__ src, unsigned short* __restrict__ dst,
                                      int N, int ld, int colOff) {
    __shared__ float tile[32][33];
    int k0 = blockIdx.x * 32;
    int n0 = blockIdx.y * 32;
    int c = threadIdx.x & 31;
    int r = threadIdx.x >> 5;            // 0..7
    #pragma unroll
    for (int i = 0; i < 32; i += 8)
        tile[r + i][c] = src[(size_t)(k0 + r + i) * N + n0 + c];
    __syncthreads();
    #pragma unroll
    for (int i = 0; i < 32; i += 8)
        dst[(size_t)(n0 + r + i) * ld + colOff + k0 + c] = f2bf(tile[c][r + i]);
}

// h0 -> h_all slot 0 (bf16); lin_w -> padded bf16 [16][2048]; zero barrier block
__global__ void small_conv_kernel(const float* __restrict__ h0, const float* __restrict__ lin_w,
                                  unsigned short* __restrict__ h_all0, unsigned short* __restrict__ lwb,
                                  unsigned int* __restrict__ bar) {
    int idx = blockIdx.x * 256 + threadIdx.x;
    if (idx < 512) bar[idx] = 0u;        // per-block flags (re-zeroed every launch)
    if (idx < Bn * Hn) {
        h_all0[idx] = f2bf(h0[idx]);
    } else {
        int j = idx - Bn * Hn;           // < 16*2048 exactly (grid sized for it)
        int o = j >> 11;
        int k = j & 2047;
        lwb[j] = (o < On) ? f2bf(lin_w[o * Hn + k]) : (unsigned short)0;
    }
}

// ---- persistent scan -----------------------------------------------------
// R10 = R9 skeleton (8 waves = 2/SIMD, XCD-pair-pinned m-groups, flag
// barrier, 8-slab reduce, depth-2 h ring) + three de-serialization changes.
// R9 post-mortem: FETCH 621->178MB confirmed (h now L2/L3-served) but time
// unchanged -> the chain is NOT h-fetch RTT. Remaining suspects attacked:
//  * K-CHUNK ROTATION (anti-convoy): all 64 group blocks used to read the
//    same h slab in the same chunk order -> 64-way same-line bursts at
//    L2/L3. Block n-index j now starts its h loop at chunk j&7 (x at j&3).
//    B-frags are preloaded PRE-ROTATED so all register indices stay static
//    (only addresses rotate; rule-#20 safe).
//  * X-PREFETCH OVERLAP: half the t+1 x-loads issue right after the
//    red-write, flying under reduce+tanh+store. Requires sync1 to NOT drain
//    vmcnt: hand-rolled "s_waitcnt lgkmcnt(0)" + raw s_barrier (hipcc's
//    __syncthreads emits vmcnt(0) which would stall on the prefetch).
//  * W0-ONLY POLL: one wave polls the 64 flags (8x less L3 flag-line
//    contention), raw-barrier release for the other 7 waves.
// Sync (proven R4-R9): relaxed agent-scope write-through h stores;
// __syncthreads (sync2) drains vmcnt(0) before the flag store; per-block
// flag; fresh h addresses each step make plain consumer loads safe.
__global__ __launch_bounds__(512, 2)
void scan_kernel(const unsigned short* __restrict__ xb,
                 const unsigned short* __restrict__ BTm,
                 unsigned short* __restrict__ h_all,
                 unsigned int* __restrict__ bar) {
    const int g = blockIdx.x;
    const int mg = (g & 7) >> 1;                        // m-group = XCD pair
    const int m0 = mg * 64;
    const int nIdx = (g >> 3) * 2 + (g & 1);            // 0..63 within group
    const int n0 = nIdx * 32;
    const int w = threadIdx.x >> 6;                     // 0..7
    const int lane = threadIdx.x & 63;
    const int quad = lane >> 4;
    const int lr = lane & 15;
    const int hoff = nIdx & 7;                          // h k-rotation
    const int xoff = nIdx & 3;                          // x k-rotation

    __shared__ float red[8][64][36];                    // pad 36: 2-way banks (free)

    const unsigned short* bp0 = BTm + (size_t)(n0 + lr) * Kc;
    const unsigned short* bp1 = BTm + (size_t)(n0 + 16 + lr) * Kc;

    const size_t xrow = (size_t)Tn * In;                // x row stride (102400)

    // flag layout: bar[mg*64 + (g&1)*32 + (g>>3)]  (bijective per group)
    const int fidx = mg * 64 + (g & 1) * 32 + (g >> 3);
    unsigned int* fl = bar + mg * 64;                   // my group's 64 flags

    // ---- one-time B-fragment preload, PRE-ROTATED by hoff/xoff ----
    s8v bx[4][2];                                       // bx[c] = x-chunk (c+xoff)&3
    s8v bh[8][2];                                       // bh[c] = h-chunk (c+hoff)&7
    #pragma unroll
    for (int c = 0; c < 4; ++c) {
        const int kq = w * 128 + (((c + xoff) & 3) * 32) + quad * 8;
        bx[c][0] = *(const s8v*)(bp0 + kq);
        bx[c][1] = *(const s8v*)(bp1 + kq);
    }
    #pragma unroll
    for (int c = 0; c < 8; ++c) {
        const int kq = In + w * 256 + (((c + hoff) & 7) * 32) + quad * 8;
        bh[c][0] = *(const s8v*)(bp0 + kq);
        bh[c][1] = *(const s8v*)(bp1 + kq);
    }

    f32x4 acc[4][2];
    #pragma unroll
    for (int mi = 0; mi < 4; ++mi)
        #pragma unroll
        for (int ni = 0; ni < 2; ++ni)
            acc[mi][ni] = (f32x4){0.f, 0.f, 0.f, 0.f};

    // ---- x-part for t=0 (rotated chunk order) ----
    {
        const unsigned short* ar0 = xb + (size_t)(m0 + lr) * xrow + w * 128 + quad * 8;
        #pragma unroll
        for (int c = 0; c < 4; ++c) {
            const unsigned short* arow = ar0 + ((c + xoff) & 3) * 32;
            s8v a0 = *(const s8v*)(arow);
            s8v a1 = *(const s8v*)(arow + 16 * xrow);
            s8v a2 = *(const s8v*)(arow + 32 * xrow);
            s8v a3 = *(const s8v*)(arow + 48 * xrow);
            acc[0][0] = __builtin_amdgcn_mfma_f32_16x16x32_bf16(a0, bx[c][0], acc[0][0], 0, 0, 0);
            acc[1][0] = __builtin_amdgcn_mfma_f32_16x16x32_bf16(a1, bx[c][0], acc[1][0], 0, 0, 0);
            acc[2][0] = __builtin_amdgcn_mfma_f32_16x16x32_bf16(a2, bx[c][0], acc[2][0], 0, 0, 0);
            acc[3][0] = __builtin_amdgcn_mfma_f32_16x16x32_bf16(a3, bx[c][0], acc[3][0], 0, 0, 0);
            acc[0][1] = __builtin_amdgcn_mfma_f32_16x16x32_bf16(a0, bx[c][1], acc[0][1], 0, 0, 0);
            acc[1][1] = __builtin_amdgcn_mfma_f32_16x16x32_bf16(a1, bx[c][1], acc[1][1], 0, 0, 0);
            acc[2][1] = __builtin_amdgcn_mfma_f32_16x16x32_bf16(a2, bx[c][1], acc[2][1], 0, 0, 0);
            acc[3][1] = __builtin_amdgcn_mfma_f32_16x16x32_bf16(a3, bx[c][1], acc[3][1], 0, 0, 0);
        }
    }

    for (int t = 0; t < Tn; ++t) {
        // ---- h-part (rotated chunk order; depth-2 ring) ----
        const unsigned short* hrow = h_all + (size_t)t * (Bn * Hn)
                                   + (size_t)(m0 + lr) * Hn + w * 256 + quad * 8;
        s8v A[2][4];
        #pragma unroll
        for (int r = 0; r < 4; ++r)
            A[0][r] = *(const s8v*)(hrow + hoff * 32 + r * 16 * Hn);
        #pragma unroll
        for (int c = 0; c < 8; ++c) {
            if (c < 7) {
                const unsigned short* p = hrow + ((c + 1 + hoff) & 7) * 32;
                #pragma unroll
                for (int r = 0; r < 4; ++r)
                    A[(c + 1) & 1][r] = *(const s8v*)(p + r * 16 * Hn);
            }
            const s8v a0 = A[c & 1][0];
            const s8v a1 = A[c & 1][1];
            const s8v a2 = A[c & 1][2];
            const s8v a3 = A[c & 1][3];
            acc[0][0] = __builtin_amdgcn_mfma_f32_16x16x32_bf16(a0, bh[c][0], acc[0][0], 0, 0, 0);
            acc[1][0] = __builtin_amdgcn_mfma_f32_16x16x32_bf16(a1, bh[c][0], acc[1][0], 0, 0, 0);
            acc[2][0] = __builtin_amdgcn_mfma_f32_16x16x32_bf16(a2, bh[c][0], acc[2][0], 0, 0, 0);
            acc[3][0] = __builtin_amdgcn_mfma_f32_16x16x32_bf16(a3, bh[c][0], acc[3][0], 0, 0, 0);
            acc[0][1] = __builtin_amdgcn_mfma_f32_16x16x32_bf16(a0, bh[c][1], acc[0][1], 0, 0, 0);
            acc[1][1] = __builtin_amdgcn_mfma_f32_16x16x32_bf16(a1, bh[c][1], acc[1][1], 0, 0, 0);
            acc[2][1] = __builtin_amdgcn_mfma_f32_16x16x32_bf16(a2, bh[c][1], acc[2][1], 0, 0, 0);
            acc[3][1] = __builtin_amdgcn_mfma_f32_16x16x32_bf16(a3, bh[c][1], acc[3][1], 0, 0, 0);
        }

        // ---- LDS reduce write: C/D layout row=quad*4+reg, col=lane&15 ----
        #pragma unroll
        for (int mi = 0; mi < 4; ++mi)
            #pragma unroll
            for (int ni = 0; ni < 2; ++ni)
                #pragma unroll
                for (int rr = 0; rr < 4; ++rr)
                    red[w][mi * 16 + quad * 4 + rr][ni * 16 + lr] = acc[mi][ni][rr];

        // ---- x-prefetch (2 of 4 chunks) for t+1: flies under the reduce ----
        s8v X[2][4];
        const unsigned short* arn = xb + (size_t)(t + 1) * In
                                  + (size_t)(m0 + lr) * xrow + w * 128 + quad * 8;
        if (t < Tn - 1) {
            #pragma unroll
            for (int c = 0; c < 2; ++c) {
                const unsigned short* p = arn + ((c + xoff) & 3) * 32;
                #pragma unroll
                for (int r = 0; r < 4; ++r)
                    X[c][r] = *(const s8v*)(p + r * 16 * xrow);
            }
        }

        // sync1: LDS-only barrier (NO vmcnt drain -> X stays in flight)
        __builtin_amdgcn_sched_barrier(0);
        asm volatile("s_waitcnt lgkmcnt(0)" ::: "memory");
        __builtin_amdgcn_s_barrier();
        __builtin_amdgcn_sched_barrier(0);

        {   // final reduce + tanh + agent-scope write-through store (8 B)
            int j = threadIdx.x << 2;
            int row = j >> 5;
            int c0 = j & 31;
            float4 s0 = *(const float4*)&red[0][row][c0];
            float4 s1 = *(const float4*)&red[1][row][c0];
            float4 s2 = *(const float4*)&red[2][row][c0];
            float4 s3 = *(const float4*)&red[3][row][c0];
            float4 s4 = *(const float4*)&red[4][row][c0];
            float4 s5 = *(const float4*)&red[5][row][c0];
            float4 s6 = *(const float4*)&red[6][row][c0];
            float4 s7 = *(const float4*)&red[7][row][c0];
            us4 o4;
            o4[0] = f2bf(fast_tanh(((s0.x + s1.x) + (s2.x + s3.x)) + ((s4.x + s5.x) + (s6.x + s7.x))));
            o4[1] = f2bf(fast_tanh(((s0.y + s1.y) + (s2.y + s3.y)) + ((s4.y + s5.y) + (s6.y + s7.y))));
            o4[2] = f2bf(fast_tanh(((s0.z + s1.z) + (s2.z + s3.z)) + ((s4.z + s5.z) + (s6.z + s7.z))));
            o4[3] = f2bf(fast_tanh(((s0.w + s1.w) + (s2.w + s3.w)) + ((s4.w + s5.w) + (s6.w + s7.w))));
            unsigned long long* dst = (unsigned long long*)
                (h_all + (size_t)(t + 1) * (Bn * Hn) + (size_t)(m0 + row) * Hn + n0 + c0);
            __hip_atomic_store(dst, __builtin_bit_cast(unsigned long long, o4),
                               __ATOMIC_RELAXED, __HIP_MEMORY_SCOPE_AGENT);
        }

        if (t < Tn - 1) {
            __syncthreads();                             // sync2: vmcnt(0) drain (h store; X done)
            const unsigned int tp1 = (unsigned int)(t + 1);

            // ---- ARRIVE: one contention-free flag store ----
            if (threadIdx.x == 0)
                __hip_atomic_store(bar + fidx, tp1, __ATOMIC_RELAXED,
                                   __HIP_MEMORY_SCOPE_AGENT);

            // ---- x-part of t+1: chunks 0,1 from prefetch; 2,3 load now ----
            #pragma unroll
            for (int mi = 0; mi < 4; ++mi)
                #pragma unroll
                for (int ni = 0; ni < 2; ++ni)
                    acc[mi][ni] = (f32x4){0.f, 0.f, 0.f, 0.f};
            #pragma unroll
            for (int c = 0; c < 2; ++c) {
                acc[0][0] = __builtin_amdgcn_mfma_f32_16x16x32_bf16(X[c][0], bx[c][0], acc[0][0], 0, 0, 0);
                acc[1][0] = __builtin_amdgcn_mfma_f32_16x16x32_bf16(X[c][1], bx[c][0], acc[1][0], 0, 0, 0);
                acc[2][0] = __builtin_amdgcn_mfma_f32_16x16x32_bf16(X[c][2], bx[c][0], acc[2][0], 0, 0, 0);
                acc[3][0] = __builtin_amdgcn_mfma_f32_16x16x32_bf16(X[c][3], bx[c][0], acc[3][0], 0, 0, 0);
                acc[0][1] = __builtin_amdgcn_mfma_f32_16x16x32_bf16(X[c][0], bx[c][1], acc[0][1], 0, 0, 0);
                acc[1][1] = __builtin_amdgcn_mfma_f32_16x16x32_bf16(X[c][1], bx[c][1], acc[1][1], 0, 0, 0);
                acc[2][1] = __builtin_amdgcn_mfma_f32_16x16x32_bf16(X[c][2], bx[c][1], acc[2][1], 0, 0, 0);
                acc[3][1] = __builtin_amdgcn_mfma_f32_16x16x32_bf16(X[c][3], bx[c][1], acc[3][1], 0, 0, 0);
            }
            #pragma unroll
            for (int c = 2; c < 4; ++c) {
                const unsigned short* p = arn + ((c + xoff) & 3) * 32;
                s8v a0 = *(const s8v*)(p);
                s8v a1 = *(const s8v*)(p + 16 * xrow);
                s8v a2 = *(const s8v*)(p + 32 * xrow);
                s8v a3 = *(const s8v*)(p + 48 * xrow);
                acc[0][0] = __builtin_amdgcn_mfma_f32_16x16x32_bf16(a0, bx[c][0], acc[0][0], 0, 0, 0);
                acc[1][0] = __builtin_amdgcn_mfma_f32_16x16x32_bf16(a1, bx[c][0], acc[1][0], 0, 0, 0);
                acc[2][0] = __builtin_amdgcn_mfma_f32_16x16x32_bf16(a2, bx[c][0], acc[2][0], 0, 0, 0);
                acc[3][0] = __builtin_amdgcn_mfma_f32_16x16x32_bf16(a3, bx[c][0], acc[3][0], 0, 0, 0);
                acc[0][1] = __builtin_amdgcn_mfma_f32_16x16x32_bf16(a0, bx[c][1], acc[0][1], 0, 0, 0);
                acc[1][1] = __builtin_amdgcn_mfma_f32_16x16x32_bf16(a1, bx[c][1], acc[1][1], 0, 0, 0);
                acc[2][1] = __builtin_amdgcn_mfma_f32_16x16x32_bf16(a2, bx[c][1], acc[2][1], 0, 0, 0);
                acc[3][1] = __builtin_amdgcn_mfma_f32_16x16x32_bf16(a3, bx[c][1], acc[3][1], 0, 0, 0);
            }

            // ---- w0-only poll + raw-barrier release ----
            if (w == 0) {
                while (true) {
                    unsigned int v = __hip_atomic_load(fl + lane, __ATOMIC_RELAXED,
                                                       __HIP_MEMORY_SCOPE_AGENT);
                    if (__all((int)(v >= tp1))) break;
                    __builtin_amdgcn_s_sleep(1);
                }
            }
            asm volatile("" ::: "memory");
            __builtin_amdgcn_s_barrier();                // sync3: release all waves
            __builtin_amdgcn_sched_barrier(0);
        }
    }
}

// ---- output projection ---------------------------------------------------
// y[b][t][o] = h_all[t+1][b][:] . lin_w[o][:] + lin_b[o]. One 16-row wave per 16 (t,b) rows.
__global__ __launch_bounds__(256)
void gemm2_kernel(const unsigned short* __restrict__ h_all, const unsigned short* __restrict__ lwb,
                  const float* __restrict__ lb, float* __restrict__ y) {
    int gw = blockIdx.x * 4 + (threadIdx.x >> 6);       // 0..1599
    int lane = threadIdx.x & 63, quad = lane >> 4, lr = lane & 15;
    int m0 = gw * 16;
    int t = m0 >> 8;
    int b0 = m0 & 255;
    const unsigned short* ah = h_all + ((size_t)(t + 1) * Bn + b0 + lr) * Hn + quad * 8;
    const unsigned short* bh = lwb + (size_t)lr * Hn + quad * 8;
    f32x4 acc0 = {0.f, 0.f, 0.f, 0.f}, acc1 = {0.f, 0.f, 0.f, 0.f};
    #pragma unroll
    for (int k0 = 0; k0 < Hn; k0 += 64) {
        s8v a0 = *(const s8v*)(ah + k0);
        s8v b0 = *(const s8v*)(bh + k0);
        acc0 = __builtin_amdgcn_mfma_f32_16x16x32_bf16(a0, b0, acc0, 0, 0, 0);
        s8v a1 = *(const s8v*)(ah + k0 + 32);
        s8v b1 = *(const s8v*)(bh + k0 + 32);
        acc1 = __builtin_amdgcn_mfma_f32_16x16x32_bf16(a1, b1, acc1, 0, 0, 0);
    }
    acc0 = acc0 + acc1;
    if (lr < On) {
        float bias = lb[lr];
        #pragma unroll
        for (int rr = 0; rr < 4; ++rr) {
            int b = b0 + quad * 4 + rr;
            y[(size_t)b * (Tn * On) + t * On + lr] = acc0[rr] + bias;
        }
    }
}

// ---- host ----------------------------------------------------------------

extern "C" void kernel_launch(void* const* d_in, const int* in_sizes, int n_in,
                              void* d_out, int out_size, void* d_ws, size_t ws_size,
                              hipStream_t stream) {
    const float* x   = (const float*)d_in[0];
    const float* h0  = (const float*)d_in[1];
    const float* Win = (const float*)d_in[2];
    const float* W   = (const float*)d_in[3];
    const float* lw  = (const float*)d_in[4];
    const float* lb  = (const float*)d_in[5];
    float* y = (float*)d_out;

    // ws layout (bf16 elems): ~171 MB total
    unsigned short* ws    = (unsigned short*)d_ws;
    unsigned short* xb    = ws;                                  // 26,214,400 elems
    unsigned short* BTm   = xb + (size_t)Bn * Tn * In;           //  6,291,456 elems [2048][3072]
    unsigned short* h_all = BTm + (size_t)Hn * Kc;               // 52,953,088 elems [(T+1)][B][H]
    unsigned short* lwb   = h_all + (size_t)(Tn + 1) * Bn * Hn;  //     32,768 elems [16][2048]
    unsigned int*   bar   = (unsigned int*)(lwb + 32768);        // 512 uints flag block

    conv_x_kernel<<<25600, 256, 0, stream>>>((const float4*)x, (ushort4*)xb);
    transpose_bf16_kernel<<<dim3(32, 64), 256, 0, stream>>>(Win, BTm, Hn, Kc, 0);
    transpose_bf16_kernel<<<dim3(64, 64), 256, 0, stream>>>(W, BTm, Hn, Kc, In);
    small_conv_kernel<<<2176, 256, 0, stream>>>(h0, lw, h_all, lwb, bar);

    scan_kernel<<<256, 512, 0, stream>>>(xb, BTm, h_all, bar);

    gemm2_kernel<<<400, 256, 0, stream>>>(h_all, lwb, lb, y);
}